// Round 7
// baseline (442.219 us; speedup 1.0000x reference)
//
#include <hip/hip_runtime.h>
#include <hip/hip_bf16.h>
#include <math.h>

#define S_LEN 2048
#define HIDDEN 4096
#define NH 32
#define NKV 8
#define HD 128
#define NQKV 6144   // NH*HD + 2*NKV*HD

typedef __bf16 bf16_t;
typedef __bf16 bf16x8 __attribute__((ext_vector_type(8)));
typedef __bf16 bf16x4 __attribute__((ext_vector_type(4)));
typedef float f32x4 __attribute__((ext_vector_type(4)));

typedef __attribute__((address_space(1))) void gvoid;
typedef __attribute__((address_space(3))) void lvoid;

__device__ __forceinline__ void gload_lds16(const void* g, void* l) {
    __builtin_amdgcn_global_load_lds((gvoid*)g, (lvoid*)l, 16, 0, 0);
}

// ---------------- cast fp32 -> bf16 (vectorized) ----------------
__global__ void cast_bf16_kernel(const float* __restrict__ in, bf16_t* __restrict__ out, int n4) {
    int stride = gridDim.x * blockDim.x;
    for (int idx = blockIdx.x * blockDim.x + threadIdx.x; idx < n4; idx += stride) {
        float4 v = ((const float4*)in)[idx];
        bf16x4 o;
        o.x = (bf16_t)v.x; o.y = (bf16_t)v.y; o.z = (bf16_t)v.z; o.w = (bf16_t)v.w;
        ((bf16x4*)out)[idx] = o;
    }
}

// ---------------- transpose + cast: in[R][C] (stride ldin) -> out[C][R] (stride ldout), bf16 ----------------
__global__ __launch_bounds__(256) void transpose_cast_kernel(const float* __restrict__ in,
                                                             bf16_t* __restrict__ out,
                                                             int ldin, int ldout) {
    __shared__ float t[32][33];
    int c0 = blockIdx.x * 32, r0 = blockIdx.y * 32;
    int tx = threadIdx.x, ty = threadIdx.y;
#pragma unroll
    for (int i = 0; i < 4; ++i)
        t[ty + i * 8][tx] = in[(size_t)(r0 + ty + i * 8) * ldin + c0 + tx];
    __syncthreads();
#pragma unroll
    for (int i = 0; i < 4; ++i)
        out[(size_t)(c0 + ty + i * 8) * ldout + r0 + tx] = (bf16_t)t[tx][ty + i * 8];
}

// ---------------- 256x256 4-phase counted-vmcnt GEMM (m201-style): C = A @ Bt^T ----------------
// BK=64, 8 waves (wm 0..1 x wn 0..3), per-wave out 128x64, LDS 128KB (2-parity dbuf x
// {A,B} x 2 halves x 128rows x 64). Staging halves ALIGNED to per-phase consumption:
//   A-half h = tile rows {wm*128 + h*64 .. +63 : wm}   (staging row128 -> grow = (r&63)+((r>>6)<<7)+h*64)
//   B-half h = tile cols {wn*64 + h*32 .. +31 : wn}    (grow = (r>>5)*64 + h*32 + (r&31))
// Phase p of tile t: {vmcnt(4); s_barrier; ds_read frags; stage 1 half of tile t+1;
//                     lgkmcnt(0); setprio(1); 16 MFMA; setprio(0)}
// Quadrants (mh,nh): P0(0,0) reads A0+B0 (12), P1(1,0) reads A1 (8), P2(1,1) reads B1 (4),
// P3(0,1) re-reads A0 (8). Stage order per tile: A0,B0,A1,B1 (of t+1).
// Ledger (2 loads/thread per stage): at P0(t) outstanding = {A0,B0,A1,B1}(t)=8 -> vmcnt(4)
// completes A0,B0; P1: outstanding {A1,B1}(t)+{A0}(t+1)=6 -> vmcnt(4) completes A1; P2:
// {B1}(t)+{A0,B0}(t+1)=6 -> completes B1; P3: trivially ok. Uniform vmcnt(4), never drains,
// 3 half-tiles in flight. Per-wave vmcnt + s_barrier => all waves' slices landed.
// Race: stage at t targets parity (t+1)&1 while reads use parity t&1. Last tile wrap-stages
// tile 0 into opposite parity (never read). Swizzle both-sides (rule #21): source chunk
// (idx&7)^(row128&7), read chunk (kk*4+g)^(c16&7); row128&7==c16&7 for all frag rows.
__global__ __launch_bounds__(512, 2) void gemm256_kernel(const bf16_t* __restrict__ A,
                                                         const bf16_t* __restrict__ Bt,
                                                         float* __restrict__ C,
                                                         int M, int N, int K) {
    __shared__ bf16_t As[2][2][128 * 64];
    __shared__ bf16_t Bs[2][2][128 * 64];
    const int tid = threadIdx.x;
    const int lane = tid & 63, w = tid >> 6;
    const int wm = w >> 2, wn = w & 3;
    const int g = lane >> 4, c16 = lane & 15;
    const int c7 = c16 & 7;

    // XCD swizzle, bm-fastest (grid % 8 == 0)
    const int nbm = M / 256;
    const int cpx = gridDim.x >> 3;
    const int swz = (blockIdx.x & 7) * cpx + (blockIdx.x >> 3);
    const int bm = swz % nbm, bn = swz / nbm;

    const bf16_t* Abase = A + (size_t)(bm * 256) * K;
    const bf16_t* Bbase = Bt + (size_t)(bn * 256) * K;

    auto stageA = [&](int par, int kt, int h) {
#pragma unroll
        for (int j = 0; j < 2; ++j) {
            int idx = j * 512 + tid;
            int r = idx >> 3;
            int grow = (r & 63) + ((r >> 6) << 7) + h * 64;
            int gcol = kt * 64 + (((idx & 7) ^ (r & 7)) << 3);
            gload_lds16(Abase + (size_t)grow * K + gcol, &As[par][h][(size_t)(j * 512 + (w << 6)) * 8]);
        }
    };
    auto stageB = [&](int par, int kt, int h) {
#pragma unroll
        for (int j = 0; j < 2; ++j) {
            int idx = j * 512 + tid;
            int r = idx >> 3;
            int grow = ((r >> 5) << 6) + h * 32 + (r & 31);
            int gcol = kt * 64 + (((idx & 7) ^ (r & 7)) << 3);
            gload_lds16(Bbase + (size_t)grow * K + gcol, &Bs[par][h][(size_t)(j * 512 + (w << 6)) * 8]);
        }
    };
    auto rdA = [&](int par, int h, bf16x8 (&a)[2][4]) {
        const bf16_t* base = &As[par][h][0];
#pragma unroll
        for (int kk = 0; kk < 2; ++kk)
#pragma unroll
            for (int mi = 0; mi < 4; ++mi) {
                int r = wm * 64 + mi * 16 + c16;
                a[kk][mi] = *(const bf16x8*)&base[r * 64 + (((kk * 4 + g) ^ c7) << 3)];
            }
    };
    auto rdB = [&](int par, int h, bf16x8 (&b)[2][2]) {
        const bf16_t* base = &Bs[par][h][0];
#pragma unroll
        for (int kk = 0; kk < 2; ++kk)
#pragma unroll
            for (int nn = 0; nn < 2; ++nn) {
                int r = wn * 32 + nn * 16 + c16;
                b[kk][nn] = *(const bf16x8*)&base[r * 64 + (((kk * 4 + g) ^ c7) << 3)];
            }
    };

#define GATE4() do { asm volatile("s_waitcnt vmcnt(4)" ::: "memory"); \
                     __builtin_amdgcn_s_barrier(); \
                     __builtin_amdgcn_sched_barrier(0); } while (0)
#define LGKM0() do { asm volatile("s_waitcnt lgkmcnt(0)" ::: "memory"); \
                     __builtin_amdgcn_sched_barrier(0); } while (0)

    f32x4 acc00[4][2], acc10[4][2], acc11[4][2], acc01[4][2];
#pragma unroll
    for (int mi = 0; mi < 4; ++mi)
#pragma unroll
        for (int nn = 0; nn < 2; ++nn) {
            acc00[mi][nn] = (f32x4){0.f, 0.f, 0.f, 0.f};
            acc10[mi][nn] = (f32x4){0.f, 0.f, 0.f, 0.f};
            acc11[mi][nn] = (f32x4){0.f, 0.f, 0.f, 0.f};
            acc01[mi][nn] = (f32x4){0.f, 0.f, 0.f, 0.f};
        }

    auto MM = [&](bf16x8 (&a)[2][4], bf16x8 (&b)[2][2], f32x4 (&acc)[4][2]) {
        __builtin_amdgcn_s_setprio(1);
#pragma unroll
        for (int kk = 0; kk < 2; ++kk)
#pragma unroll
            for (int mi = 0; mi < 4; ++mi)
#pragma unroll
                for (int nn = 0; nn < 2; ++nn)
                    acc[mi][nn] = __builtin_amdgcn_mfma_f32_16x16x32_bf16(a[kk][mi], b[kk][nn], acc[mi][nn], 0, 0, 0);
        __builtin_amdgcn_s_setprio(0);
    };

    const int NT = K / 64;
    // prologue: 4 halves of tile 0, order A0,B0,A1,B1
    stageA(0, 0, 0); stageB(0, 0, 0); stageA(0, 0, 1); stageB(0, 0, 1);

    bf16x8 a[2][4], b[2][2];
    for (int t = 0; t < NT; ++t) {
        const int par = t & 1, nxt = par ^ 1;
        const int nk = (t + 1 < NT) ? t + 1 : 0;   // wrap-stage keeps ledger uniform
        // P0: quadrant (0,0)
        GATE4();
        rdA(par, 0, a); rdB(par, 0, b);
        stageA(nxt, nk, 0);
        LGKM0();
        MM(a, b, acc00);
        // P1: quadrant (1,0)
        GATE4();
        rdA(par, 1, a);
        stageB(nxt, nk, 0);
        LGKM0();
        MM(a, b, acc10);
        // P2: quadrant (1,1)
        GATE4();
        rdB(par, 1, b);
        stageA(nxt, nk, 1);
        LGKM0();
        MM(a, b, acc11);
        // P3: quadrant (0,1), re-read A-half0
        GATE4();
        rdA(par, 0, a);
        stageB(nxt, nk, 1);
        LGKM0();
        MM(a, b, acc01);
    }
#undef GATE4
#undef LGKM0

    auto wr = [&](f32x4 (&acc)[4][2], int mh, int nh) {
#pragma unroll
        for (int mi = 0; mi < 4; ++mi)
#pragma unroll
            for (int nn = 0; nn < 2; ++nn) {
                int col = bn * 256 + wn * 64 + nh * 32 + nn * 16 + c16;
#pragma unroll
                for (int r = 0; r < 4; ++r) {
                    int row = bm * 256 + wm * 128 + mh * 64 + mi * 16 + g * 4 + r;
                    C[(size_t)row * N + col] = acc[mi][nn][r];
                }
            }
    };
    wr(acc00, 0, 0); wr(acc10, 1, 0); wr(acc11, 1, 1); wr(acc01, 0, 1);
}

// ---------------- RoPE: in fp32 [S][ld] (head block at col h*128) -> out bf16 [H][S][128] ----------------
__global__ void rope_kernel(const float* __restrict__ in, bf16_t* __restrict__ out,
                            const int* __restrict__ pos, int H, int ld, float scale) {
    int idx = blockIdx.x * blockDim.x + threadIdx.x;
    int total = S_LEN * H * 64;
    if (idx >= total) return;
    int d = idx & 63;
    int h = (idx >> 6) % H;
    int s = idx / (64 * H);
    const float* base = in + (size_t)s * ld + h * HD;
    float x0 = base[d], x1 = base[d + 64];
    float p = (float)pos[s];
    float invf = __expf(-0.14391156831212787f * (float)d);  // ln(10000)/64
    float f = p * invf;
    float sn, cs;
    __sincosf(f, &sn, &cs);
    float o0 = (x0 * cs - x1 * sn) * scale;
    float o1 = (x1 * cs + x0 * sn) * scale;
    bf16_t* ob = out + ((size_t)h * S_LEN + s) * HD;
    ob[d] = (bf16_t)o0;
    ob[d + 64] = (bf16_t)o1;
}

// ---------------- flash attention (cooperative LDS staging, 2-phase pipeline) ----------------
#define PLD 72
__global__ __launch_bounds__(256) void attn_kernel(const bf16_t* __restrict__ Q,
                                                   const bf16_t* __restrict__ K,
                                                   const bf16_t* __restrict__ Vt,
                                                   bf16_t* __restrict__ O) {
    __shared__ bf16_t Ks[2][64 * 128];   // [kv row][d], swizzled chunks
    __shared__ bf16_t Vs[2][128 * 64];   // [d][kv], swizzled chunks
    __shared__ bf16_t Pl[4][16 * PLD];
    const int tid = threadIdx.x;
    const int lane = tid & 63, w = tid >> 6;
    const int bid = blockIdx.x;
    const int h = bid & 31;
    const int x = bid >> 5;
    const int kv = h >> 2;               // N_REP = 4
    const int qb = x * 64 + w * 16;
    const int g = lane >> 4, c16 = lane & 15;
    const int c7 = c16 & 7;
    const bf16_t* Qh = Q + (size_t)h * S_LEN * HD;
    const bf16_t* Kh = K + (size_t)kv * S_LEN * HD;
    const bf16_t* Vh = Vt + (size_t)kv * HD * S_LEN;
    bf16_t* P = Pl[w];

    auto stage = [&](int buf, int kb) {
        bf16_t* Kd = Ks[buf];
        bf16_t* Vd = Vs[buf];
#pragma unroll
        for (int j = 0; j < 4; ++j) {
            int i = w * 4 + j;
            {   // K: instr covers 4 rows of 256B; lane l -> row 4i+(l>>4), chunk l&15
                int row = 4 * i + (lane >> 4);
                int sc = (lane & 15) ^ (row & 7);
                gload_lds16(Kh + (size_t)(kb + row) * HD + sc * 8, Kd + i * 512);
            }
            {   // V: instr covers 8 rows of 128B; lane l -> row 8i+(l>>3), chunk l&7
                int row = 8 * i + (lane >> 3);
                int sc = (lane & 7) ^ ((lane >> 3) & 7);
                gload_lds16(Vh + (size_t)row * S_LEN + kb + sc * 8, Vd + i * 512);
            }
        }
    };

    bf16x8 qf[4];
#pragma unroll
    for (int c = 0; c < 4; ++c)
        qf[c] = *(const bf16x8*)(Qh + (size_t)(qb + c16) * HD + c * 32 + g * 8);

    f32x4 acc_o[8];
#pragma unroll
    for (int dt = 0; dt < 8; ++dt) acc_o[dt] = (f32x4){0.f, 0.f, 0.f, 0.f};
    float m[4] = {-1e30f, -1e30f, -1e30f, -1e30f};
    float l[4] = {0.f, 0.f, 0.f, 0.f};

    const int nkt = x + 1;               // KVBLK=64; diagonal tile is last
    stage(0, 0);
    __syncthreads();
    int cur = 0;

    for (int kt = 0; kt < nkt; ++kt) {
        if (kt + 1 < nkt) stage(cur ^ 1, (kt + 1) * 64);
        const int kb = kt * 64;
        const bf16_t* Kb = Ks[cur];
        const bf16_t* Vb = Vs[cur];
        const bool diag = (kt == nkt - 1);

        f32x4 sacc[4];
#pragma unroll
        for (int t = 0; t < 4; ++t) sacc[t] = (f32x4){0.f, 0.f, 0.f, 0.f};
#pragma unroll
        for (int t = 0; t < 4; ++t) {
            const bf16_t* krow = Kb + (t * 16 + c16) * 128;
#pragma unroll
            for (int cc = 0; cc < 4; ++cc) {
                bf16x8 kf = *(const bf16x8*)(krow + (((cc * 4 + g) ^ c7) * 8));
                sacc[t] = __builtin_amdgcn_mfma_f32_16x16x32_bf16(qf[cc], kf, sacc[t], 0, 0, 0);
            }
        }
        float p[4][4], alpha[4];
#pragma unroll
        for (int r = 0; r < 4; ++r) {
            int qq = qb + g * 4 + r;
            float s[4];
#pragma unroll
            for (int t = 0; t < 4; ++t)
                s[t] = (!diag || (kb + t * 16 + c16 <= qq)) ? sacc[t][r] : -1e30f;
            float mx = fmaxf(fmaxf(s[0], s[1]), fmaxf(s[2], s[3]));
            mx = fmaxf(mx, __shfl_xor(mx, 1));
            mx = fmaxf(mx, __shfl_xor(mx, 2));
            mx = fmaxf(mx, __shfl_xor(mx, 4));
            mx = fmaxf(mx, __shfl_xor(mx, 8));
            float mn = fmaxf(m[r], mx);
            alpha[r] = __expf(m[r] - mn);
            m[r] = mn;
            float rs = 0.f;
#pragma unroll
            for (int t = 0; t < 4; ++t) {
                p[t][r] = __expf(s[t] - mn);
                rs += p[t][r];
            }
            rs += __shfl_xor(rs, 1);
            rs += __shfl_xor(rs, 2);
            rs += __shfl_xor(rs, 4);
            rs += __shfl_xor(rs, 8);
            l[r] = l[r] * alpha[r] + rs;
        }
#pragma unroll
        for (int dt = 0; dt < 8; ++dt)
#pragma unroll
            for (int r = 0; r < 4; ++r) acc_o[dt][r] *= alpha[r];
#pragma unroll
        for (int t = 0; t < 4; ++t)
#pragma unroll
            for (int r = 0; r < 4; ++r)
                P[(g * 4 + r) * PLD + t * 16 + c16] = (bf16_t)p[t][r];
        bf16x8 pf[2];
        pf[0] = *(const bf16x8*)(P + c16 * PLD + g * 8);
        pf[1] = *(const bf16x8*)(P + c16 * PLD + 32 + g * 8);
#pragma unroll
        for (int dt = 0; dt < 8; ++dt) {
            const bf16_t* vrow = Vb + (dt * 16 + c16) * 64;
            bf16x8 vf0 = *(const bf16x8*)(vrow + ((g ^ c7) * 8));
            bf16x8 vf1 = *(const bf16x8*)(vrow + (((4 + g) ^ c7) * 8));
            acc_o[dt] = __builtin_amdgcn_mfma_f32_16x16x32_bf16(pf[0], vf0, acc_o[dt], 0, 0, 0);
            acc_o[dt] = __builtin_amdgcn_mfma_f32_16x16x32_bf16(pf[1], vf1, acc_o[dt], 0, 0, 0);
        }
        __syncthreads();
        cur ^= 1;
    }
    float inv_l[4];
#pragma unroll
    for (int r = 0; r < 4; ++r) inv_l[r] = 1.f / l[r];
#pragma unroll
    for (int dt = 0; dt < 8; ++dt)
#pragma unroll
        for (int r = 0; r < 4; ++r)
            O[(size_t)(qb + g * 4 + r) * HIDDEN + h * HD + dt * 16 + c16] =
                (bf16_t)(acc_o[dt][r] * inv_l[r]);
}

// ---------------- host ----------------
extern "C" void kernel_launch(void* const* d_in, const int* in_sizes, int n_in,
                              void* d_out, int out_size, void* d_ws, size_t ws_size,
                              hipStream_t stream) {
    const float* hs = (const float*)d_in[0];
    const float* Wq = (const float*)d_in[1];
    const float* Wk = (const float*)d_in[2];
    const float* Wv = (const float*)d_in[3];
    const float* Wo = (const float*)d_in[4];
    const int* pos = (const int*)d_in[6];
    float* out = (float*)d_out;

    char* ws = (char*)d_ws;
    size_t off = 0;
    auto alloc = [&](size_t bytes) -> void* {
        void* p = ws + off;
        off += (bytes + 255) & ~(size_t)255;
        return p;
    };
    bf16_t* hB    = (bf16_t*)alloc((size_t)S_LEN * HIDDEN * 2);
    bf16_t* WqkvT = (bf16_t*)alloc((size_t)NQKV * HIDDEN * 2);   // [6144][4096]
    bf16_t* WoT   = (bf16_t*)alloc((size_t)HIDDEN * HIDDEN * 2);
    float*  QKV   = (float*)alloc((size_t)S_LEN * NQKV * 4);     // [2048][6144]
    bf16_t* Qr    = (bf16_t*)alloc((size_t)NH * S_LEN * HD * 2);
    bf16_t* Kr    = (bf16_t*)alloc((size_t)NKV * S_LEN * HD * 2);
    bf16_t* Vt    = (bf16_t*)alloc((size_t)NKV * HD * S_LEN * 2);
    bf16_t* Oat   = (bf16_t*)alloc((size_t)S_LEN * HIDDEN * 2);

    dim3 tb(32, 8);
    // 1. cast hidden to bf16
    cast_bf16_kernel<<<2048, 256, 0, stream>>>(hs, hB, S_LEN * HIDDEN / 4);
    // 2. transpose-cast weights into fused [6144][4096]
    transpose_cast_kernel<<<dim3(HIDDEN / 32, HIDDEN / 32), tb, 0, stream>>>(Wq, WqkvT, HIDDEN, HIDDEN);
    transpose_cast_kernel<<<dim3(1024 / 32, HIDDEN / 32), tb, 0, stream>>>(Wk, WqkvT + (size_t)4096 * HIDDEN, 1024, HIDDEN);
    transpose_cast_kernel<<<dim3(1024 / 32, HIDDEN / 32), tb, 0, stream>>>(Wv, WqkvT + (size_t)5120 * HIDDEN, 1024, HIDDEN);
    transpose_cast_kernel<<<dim3(HIDDEN / 32, HIDDEN / 32), tb, 0, stream>>>(Wo, WoT, HIDDEN, HIDDEN);
    // 3. fused QKV projection: [2048][4096] @ [4096][6144]^T-layout -> [2048][6144], 192 blocks
    gemm256_kernel<<<(S_LEN / 256) * (NQKV / 256), 512, 0, stream>>>(hB, WqkvT, QKV, S_LEN, NQKV, HIDDEN);
    // 4. RoPE (fold 1/sqrt(128) into Q)
    rope_kernel<<<(S_LEN * NH * 64 + 255) / 256, 256, 0, stream>>>(QKV, Qr, pos, NH, NQKV, 0.08838834764831843f);
    rope_kernel<<<(S_LEN * NKV * 64 + 255) / 256, 256, 0, stream>>>(QKV + 4096, Kr, pos, NKV, NQKV, 1.0f);
    // 5. V transpose: [S][1024] (stride 6144) -> [1024][2048] == [NKV][128][S]
    transpose_cast_kernel<<<dim3(1024 / 32, S_LEN / 32), tb, 0, stream>>>(QKV + 5120, Vt, NQKV, S_LEN);
    // 6. flash attention
    attn_kernel<<<1024, 256, 0, stream>>>(Qr, Kr, Vt, Oat);
    // 7. output projection, 128 blocks
    gemm256_kernel<<<(S_LEN / 256) * (HIDDEN / 256), 512, 0, stream>>>(Oat, WoT, out, S_LEN, HIDDEN, HIDDEN);
}

// Round 9
// 384.648 us; speedup vs baseline: 1.1497x; 1.1497x over previous
//
#include <hip/hip_runtime.h>
#include <hip/hip_bf16.h>

#define S_LEN 2048
#define HIDDEN 4096
#define NH 32
#define NKV 8
#define HD 128
#define NQKV 6144   // NH*HD + 2*NKV*HD

typedef __bf16 bf16_t;
typedef __bf16 bf16x8 __attribute__((ext_vector_type(8)));
typedef __bf16 bf16x4 __attribute__((ext_vector_type(4)));
typedef float f32x4 __attribute__((ext_vector_type(4)));

typedef __attribute__((address_space(1))) void gvoid;
typedef __attribute__((address_space(3))) void lvoid;

__device__ __forceinline__ void gload_lds16(const void* g, void* l) {
    __builtin_amdgcn_global_load_lds((gvoid*)g, (lvoid*)l, 16, 0, 0);
}

__device__ __forceinline__ float fast_exp2(float x) {
    return __builtin_amdgcn_exp2f(x);   // v_exp_f32 (2^x native)
}

// ---------------- cast fp32 -> bf16 (vectorized) ----------------
__global__ void cast_bf16_kernel(const float* __restrict__ in, bf16_t* __restrict__ out, int n4) {
    int stride = gridDim.x * blockDim.x;
    for (int idx = blockIdx.x * blockDim.x + threadIdx.x; idx < n4; idx += stride) {
        float4 v = ((const float4*)in)[idx];
        bf16x4 o;
        o.x = (bf16_t)v.x; o.y = (bf16_t)v.y; o.z = (bf16_t)v.z; o.w = (bf16_t)v.w;
        ((bf16x4*)out)[idx] = o;
    }
}

// ---------------- transpose + cast: in[R][C] fp32 (stride ldin) -> out[C][R] bf16 (stride ldout) ----------------
__global__ __launch_bounds__(256) void transpose_cast_kernel(const float* __restrict__ in,
                                                             bf16_t* __restrict__ out,
                                                             int ldin, int ldout) {
    __shared__ float t[32][33];
    int c0 = blockIdx.x * 32, r0 = blockIdx.y * 32;
    int tx = threadIdx.x, ty = threadIdx.y;
#pragma unroll
    for (int i = 0; i < 4; ++i)
        t[ty + i * 8][tx] = in[(size_t)(r0 + ty + i * 8) * ldin + c0 + tx];
    __syncthreads();
#pragma unroll
    for (int i = 0; i < 4; ++i)
        out[(size_t)(c0 + ty + i * 8) * ldout + r0 + tx] = (bf16_t)t[tx][ty + i * 8];
}

// ---------------- transpose bf16 -> bf16: in[R][C] (stride ldin) -> out[C][R] (stride ldout) ----------------
__global__ __launch_bounds__(256) void transpose_bf16_kernel(const bf16_t* __restrict__ in,
                                                             bf16_t* __restrict__ out,
                                                             int ldin, int ldout) {
    __shared__ float t[32][33];
    int c0 = blockIdx.x * 32, r0 = blockIdx.y * 32;
    int tx = threadIdx.x, ty = threadIdx.y;
#pragma unroll
    for (int i = 0; i < 4; ++i)
        t[ty + i * 8][tx] = (float)in[(size_t)(r0 + ty + i * 8) * ldin + c0 + tx];
    __syncthreads();
#pragma unroll
    for (int i = 0; i < 4; ++i)
        out[(size_t)(c0 + ty + i * 8) * ldout + r0 + tx] = (bf16_t)t[tx][ty + i * 8];
}

// ---------------- ring-3 counted-vmcnt GEMM: C[M][N] = A[M][K] @ Bt[N][K]^T ----------------
// 128x256 tile, BK=32 per phase, 8 waves (2m x 4n, 64x64 out each), 512 threads.
// LDS ring of 3 K-chunk slots = 72 KiB -> 2 blocks/CU. Per phase:
// {vmcnt(3); s_barrier; [setprio(1)] ds_read frags INTERLEAVED by compiler with 16 MFMA
//  (counted lgkmcnt, NO explicit lgkm fence); stage chunk t+2 (3 gloads); [setprio(0)]}.
// Ledger: chunk t staged at phase t-2; outstanding at gate-t = stage(t-1) = 3 -> vmcnt(3)
// completes chunk t exactly, never drains. Race-free: slot(t+2)%3 == slot(t-1), whose
// readers completed before barrier-t. Wrap-stage keeps ledger uniform.
// Swizzle (rule #21): linear LDS dest; global chunk (l&3)^((l>>3)&3); read chunk g^((c16>>1)&3).
template<typename OutT>
__global__ __launch_bounds__(512, 2) void gemm_ring_kernel(const bf16_t* __restrict__ A,
                                                           const bf16_t* __restrict__ Bt,
                                                           OutT* __restrict__ C,
                                                           int M, int N, int K) {
    __shared__ bf16_t As[3][128 * 32];
    __shared__ bf16_t Bs[3][256 * 32];
    const int tid = threadIdx.x;
    const int lane = tid & 63, w = tid >> 6;
    const int wm = w >> 2, wn = w & 3;
    const int g = lane >> 4, c16 = lane & 15;
    const int srow = lane >> 2;                              // row within a 16-row DMA instr
    const int scg = ((lane & 3) ^ ((lane >> 3) & 3)) * 8;    // pre-swizzled global chunk (elems)
    const int rdc = (g ^ ((c16 >> 1) & 3)) * 8;              // swizzled read chunk (elems)

    // XCD swizzle, bm-fastest
    const int nbm = M / 128;
    const int cpx = gridDim.x >> 3;
    const int bid = blockIdx.x;
    const int swz = (bid & 7) * cpx + (bid >> 3);
    const int bm = swz % nbm, bn = swz / nbm;

    const bf16_t* Ab = A + (size_t)(bm * 128) * K;
    const bf16_t* Bb = Bt + (size_t)(bn * 256) * K;

    auto stage = [&](int slot, int kt) {
        const bf16_t* Ak = Ab + (size_t)kt * 32;
        const bf16_t* Bk = Bb + (size_t)kt * 32;
        {   // A: 8 instrs total, 1 per wave: rows 16w..16w+15
            int rb = 16 * w;
            gload_lds16(Ak + (size_t)(rb + srow) * K + scg, &As[slot][rb * 32]);
        }
#pragma unroll
        for (int j = 0; j < 2; ++j) {   // B: 16 instrs, 2 per wave
            int rb = 32 * w + 16 * j;
            gload_lds16(Bk + (size_t)(rb + srow) * K + scg, &Bs[slot][rb * 32]);
        }
    };

    f32x4 acc[4][4];
#pragma unroll
    for (int i = 0; i < 4; ++i)
#pragma unroll
        for (int j = 0; j < 4; ++j)
            acc[i][j] = (f32x4){0.f, 0.f, 0.f, 0.f};

    const int NT = K / 32;
    stage(0, 0);
    stage(1, 1);

    int slot = 0, slot2 = 2;           // slot = t%3, slot2 = (t+2)%3
    for (int t = 0; t < NT; ++t) {
        asm volatile("s_waitcnt vmcnt(3)" ::: "memory");
        __builtin_amdgcn_s_barrier();
        __builtin_amdgcn_sched_barrier(0);
        __builtin_amdgcn_s_setprio(1);

        bf16x8 af[4], bf[4];
#pragma unroll
        for (int i = 0; i < 4; ++i) {
            int arow = wm * 64 + i * 16 + c16;
            af[i] = *(const bf16x8*)&As[slot][arow * 32 + rdc];
            int brow = wn * 64 + i * 16 + c16;
            bf[i] = *(const bf16x8*)&Bs[slot][brow * 32 + rdc];
        }
        int nk = t + 2;
        if (nk >= NT) nk -= NT;        // wrap-stage: keeps ledger uniform, never read
        stage(slot2, nk);

        // NO lgkmcnt(0) fence: compiler interleaves ds_reads with MFMAs (counted lgkmcnt)
#pragma unroll
        for (int i = 0; i < 4; ++i)
#pragma unroll
            for (int j = 0; j < 4; ++j)
                acc[i][j] = __builtin_amdgcn_mfma_f32_16x16x32_bf16(af[i], bf[j], acc[i][j], 0, 0, 0);
        __builtin_amdgcn_s_setprio(0);

        slot = (slot + 1) % 3;
        slot2 = (slot2 + 1) % 3;
    }

#pragma unroll
    for (int mi = 0; mi < 4; ++mi)
#pragma unroll
        for (int ni = 0; ni < 4; ++ni) {
            int col = bn * 256 + wn * 64 + ni * 16 + c16;
#pragma unroll
            for (int r = 0; r < 4; ++r) {
                int row = bm * 128 + wm * 64 + mi * 16 + g * 4 + r;
                C[(size_t)row * N + col] = (OutT)acc[mi][ni][r];
            }
        }
}

// ---------------- RoPE: in bf16 [S][ld] (head block at col h*128) -> out bf16 [H][S][128] ----------------
__global__ void rope_kernel(const bf16_t* __restrict__ in, bf16_t* __restrict__ out,
                            const int* __restrict__ pos, int H, int ld, float scale) {
    int idx = blockIdx.x * blockDim.x + threadIdx.x;
    int total = S_LEN * H * 64;
    if (idx >= total) return;
    int d = idx & 63;
    int h = (idx >> 6) % H;
    int s = idx / (64 * H);
    const bf16_t* base = in + (size_t)s * ld + h * HD;
    float x0 = (float)base[d], x1 = (float)base[d + 64];
    float p = (float)pos[s];
    float invf = fast_exp2(-0.20762050593046935f * (float)d);  // log2(10000)/64
    float f = p * invf;
    float sn, cs;
    __sincosf(f, &sn, &cs);
    float o0 = (x0 * cs - x1 * sn) * scale;
    float o1 = (x1 * cs + x0 * sn) * scale;
    bf16_t* ob = out + ((size_t)h * S_LEN + s) * HD;
    ob[d] = (bf16_t)o0;
    ob[d + 64] = (bf16_t)o1;
}

// ---------------- flash attention (cooperative LDS staging, exp2-domain softmax) ----------------
// Q pre-scaled by log2(e)/sqrt(128) so softmax uses v_exp_f32 (2^x) directly.
#define PLD 72
__global__ __launch_bounds__(256) void attn_kernel(const bf16_t* __restrict__ Q,
                                                   const bf16_t* __restrict__ K,
                                                   const bf16_t* __restrict__ Vt,
                                                   bf16_t* __restrict__ O) {
    __shared__ bf16_t Ks[2][64 * 128];   // [kv row][d], swizzled chunks
    __shared__ bf16_t Vs[2][128 * 64];   // [d][kv], swizzled chunks
    __shared__ bf16_t Pl[4][16 * PLD];
    const int tid = threadIdx.x;
    const int lane = tid & 63, w = tid >> 6;
    const int bid = blockIdx.x;
    const int h = bid & 31;
    const int x = bid >> 5;
    const int kv = h >> 2;               // N_REP = 4
    const int qb = x * 64 + w * 16;
    const int g = lane >> 4, c16 = lane & 15;
    const int c7 = c16 & 7;
    const bf16_t* Qh = Q + (size_t)h * S_LEN * HD;
    const bf16_t* Kh = K + (size_t)kv * S_LEN * HD;
    const bf16_t* Vh = Vt + (size_t)kv * HD * S_LEN;
    bf16_t* P = Pl[w];

    auto stage = [&](int buf, int kb) {
        bf16_t* Kd = Ks[buf];
        bf16_t* Vd = Vs[buf];
#pragma unroll
        for (int j = 0; j < 4; ++j) {
            int i = w * 4 + j;
            {   // K: instr covers 4 rows of 256B; lane l -> row 4i+(l>>4), chunk l&15
                int row = 4 * i + (lane >> 4);
                int sc = (lane & 15) ^ (row & 7);
                gload_lds16(Kh + (size_t)(kb + row) * HD + sc * 8, Kd + i * 512);
            }
            {   // V: instr covers 8 rows of 128B; lane l -> row 8i+(l>>3), chunk l&7
                int row = 8 * i + (lane >> 3);
                int sc = (lane & 7) ^ ((lane >> 3) & 7);
                gload_lds16(Vh + (size_t)row * S_LEN + kb + sc * 8, Vd + i * 512);
            }
        }
    };

    bf16x8 qf[4];
#pragma unroll
    for (int c = 0; c < 4; ++c)
        qf[c] = *(const bf16x8*)(Qh + (size_t)(qb + c16) * HD + c * 32 + g * 8);

    f32x4 acc_o[8];
#pragma unroll
    for (int dt = 0; dt < 8; ++dt) acc_o[dt] = (f32x4){0.f, 0.f, 0.f, 0.f};
    float m[4] = {-1e30f, -1e30f, -1e30f, -1e30f};
    float l[4] = {0.f, 0.f, 0.f, 0.f};

    const int nkt = x + 1;               // KVBLK=64; diagonal tile is last
    stage(0, 0);
    __syncthreads();
    int cur = 0;

    for (int kt = 0; kt < nkt; ++kt) {
        if (kt + 1 < nkt) stage(cur ^ 1, (kt + 1) * 64);
        const int kb = kt * 64;
        const bf16_t* Kb = Ks[cur];
        const bf16_t* Vb = Vs[cur];
        const bool diag = (kt == nkt - 1);

        f32x4 sacc[4];
#pragma unroll
        for (int t = 0; t < 4; ++t) sacc[t] = (f32x4){0.f, 0.f, 0.f, 0.f};
#pragma unroll
        for (int t = 0; t < 4; ++t) {
            const bf16_t* krow = Kb + (t * 16 + c16) * 128;
#pragma unroll
            for (int cc = 0; cc < 4; ++cc) {
                bf16x8 kf = *(const bf16x8*)(krow + (((cc * 4 + g) ^ c7) * 8));
                sacc[t] = __builtin_amdgcn_mfma_f32_16x16x32_bf16(qf[cc], kf, sacc[t], 0, 0, 0);
            }
        }
        float p[4][4], alpha[4];
#pragma unroll
        for (int r = 0; r < 4; ++r) {
            int qq = qb + g * 4 + r;
            float s[4];
#pragma unroll
            for (int t = 0; t < 4; ++t)
                s[t] = (!diag || (kb + t * 16 + c16 <= qq)) ? sacc[t][r] : -1e30f;
            float mx = fmaxf(fmaxf(s[0], s[1]), fmaxf(s[2], s[3]));
            mx = fmaxf(mx, __shfl_xor(mx, 1));
            mx = fmaxf(mx, __shfl_xor(mx, 2));
            mx = fmaxf(mx, __shfl_xor(mx, 4));
            mx = fmaxf(mx, __shfl_xor(mx, 8));
            float mn = fmaxf(m[r], mx);
            alpha[r] = fast_exp2(m[r] - mn);
            m[r] = mn;
            float rs = 0.f;
#pragma unroll
            for (int t = 0; t < 4; ++t) {
                p[t][r] = fast_exp2(s[t] - mn);
                rs += p[t][r];
            }
            rs += __shfl_xor(rs, 1);
            rs += __shfl_xor(rs, 2);
            rs += __shfl_xor(rs, 4);
            rs += __shfl_xor(rs, 8);
            l[r] = l[r] * alpha[r] + rs;
        }
#pragma unroll
        for (int dt = 0; dt < 8; ++dt)
#pragma unroll
            for (int r = 0; r < 4; ++r) acc_o[dt][r] *= alpha[r];
#pragma unroll
        for (int t = 0; t < 4; ++t)
#pragma unroll
            for (int r = 0; r < 4; ++r)
                P[(g * 4 + r) * PLD + t * 16 + c16] = (bf16_t)p[t][r];
        bf16x8 pf[2];
        pf[0] = *(const bf16x8*)(P + c16 * PLD + g * 8);
        pf[1] = *(const bf16x8*)(P + c16 * PLD + 32 + g * 8);
#pragma unroll
        for (int dt = 0; dt < 8; ++dt) {
            const bf16_t* vrow = Vb + (dt * 16 + c16) * 64;
            bf16x8 vf0 = *(const bf16x8*)(vrow + ((g ^ c7) * 8));
            bf16x8 vf1 = *(const bf16x8*)(vrow + (((4 + g) ^ c7) * 8));
            acc_o[dt] = __builtin_amdgcn_mfma_f32_16x16x32_bf16(pf[0], vf0, acc_o[dt], 0, 0, 0);
            acc_o[dt] = __builtin_amdgcn_mfma_f32_16x16x32_bf16(pf[1], vf1, acc_o[dt], 0, 0, 0);
        }
        __syncthreads();
        cur ^= 1;
    }
    float inv_l[4];
#pragma unroll
    for (int r = 0; r < 4; ++r) inv_l[r] = 1.f / l[r];
#pragma unroll
    for (int dt = 0; dt < 8; ++dt)
#pragma unroll
        for (int r = 0; r < 4; ++r)
            O[(size_t)(qb + g * 4 + r) * HIDDEN + h * HD + dt * 16 + c16] =
                (bf16_t)(acc_o[dt][r] * inv_l[r]);
}

// ---------------- host ----------------
extern "C" void kernel_launch(void* const* d_in, const int* in_sizes, int n_in,
                              void* d_out, int out_size, void* d_ws, size_t ws_size,
                              hipStream_t stream) {
    const float* hs = (const float*)d_in[0];
    const float* Wq = (const float*)d_in[1];
    const float* Wk = (const float*)d_in[2];
    const float* Wv = (const float*)d_in[3];
    const float* Wo = (const float*)d_in[4];
    const int* pos = (const int*)d_in[6];
    float* out = (float*)d_out;

    char* ws = (char*)d_ws;
    size_t off = 0;
    auto alloc = [&](size_t bytes) -> void* {
        void* p = ws + off;
        off += (bytes + 255) & ~(size_t)255;
        return p;
    };
    bf16_t* hB    = (bf16_t*)alloc((size_t)S_LEN * HIDDEN * 2);
    bf16_t* WqkvT = (bf16_t*)alloc((size_t)NQKV * HIDDEN * 2);   // [6144][4096]
    bf16_t* WoT   = (bf16_t*)alloc((size_t)HIDDEN * HIDDEN * 2);
    bf16_t* QKV   = (bf16_t*)alloc((size_t)S_LEN * NQKV * 2);    // [2048][6144] bf16
    bf16_t* Qr    = (bf16_t*)alloc((size_t)NH * S_LEN * HD * 2);
    bf16_t* Kr    = (bf16_t*)alloc((size_t)NKV * S_LEN * HD * 2);
    bf16_t* Vt    = (bf16_t*)alloc((size_t)NKV * HD * S_LEN * 2);
    bf16_t* Oat   = (bf16_t*)alloc((size_t)S_LEN * HIDDEN * 2);

    dim3 tb(32, 8);
    // 1. cast hidden to bf16
    cast_bf16_kernel<<<2048, 256, 0, stream>>>(hs, hB, S_LEN * HIDDEN / 4);
    // 2. transpose-cast weights into fused [6144][4096]
    transpose_cast_kernel<<<dim3(HIDDEN / 32, HIDDEN / 32), tb, 0, stream>>>(Wq, WqkvT, HIDDEN, HIDDEN);
    transpose_cast_kernel<<<dim3(1024 / 32, HIDDEN / 32), tb, 0, stream>>>(Wk, WqkvT + (size_t)4096 * HIDDEN, 1024, HIDDEN);
    transpose_cast_kernel<<<dim3(1024 / 32, HIDDEN / 32), tb, 0, stream>>>(Wv, WqkvT + (size_t)5120 * HIDDEN, 1024, HIDDEN);
    transpose_cast_kernel<<<dim3(HIDDEN / 32, HIDDEN / 32), tb, 0, stream>>>(Wo, WoT, HIDDEN, HIDDEN);
    // 3. fused QKV projection -> bf16 [2048][6144], 384 blocks (full chip)
    gemm_ring_kernel<bf16_t><<<(S_LEN / 128) * (NQKV / 256), 512, 0, stream>>>(hB, WqkvT, QKV, S_LEN, NQKV, HIDDEN);
    // 4. RoPE; Q scale = log2(e)/sqrt(128) for exp2-domain softmax
    rope_kernel<<<(S_LEN * NH * 64 + 255) / 256, 256, 0, stream>>>(QKV, Qr, pos, NH, NQKV, 0.1275174310f);
    rope_kernel<<<(S_LEN * NKV * 64 + 255) / 256, 256, 0, stream>>>(QKV + 4096, Kr, pos, NKV, NQKV, 1.0f);
    // 5. V transpose: bf16 [S][1024] (stride 6144) -> [1024][2048] == [NKV][128][S]
    transpose_bf16_kernel<<<dim3(1024 / 32, S_LEN / 32), tb, 0, stream>>>(QKV + 5120, Vt, NQKV, S_LEN);
    // 6. flash attention
    attn_kernel<<<1024, 256, 0, stream>>>(Qr, Kr, Vt, Oat);
    // 7. output projection (fp32 out), 256 blocks
    gemm_ring_kernel<float><<<(S_LEN / 128) * (HIDDEN / 256), 512, 0, stream>>>(Oat, WoT, out, S_LEN, HIDDEN, HIDDEN);
}